// Round 6
// baseline (190.602 us; speedup 1.0000x reference)
//
#include <hip/hip_runtime.h>

// Problem constants (N=4096 rows, D=2048 cols, T=0.5 -> 1/T = 2)
#define NR 4096
#define DD 2048
#define INV_T 2.0f
// fp4 path (gemm): a_n*64 ~ N(0,1.41) into e2m1 range ±6 (±4.2 sigma);
// MFMA acc = 4096*sim
#define QS4 64.0f
#define ACC4_TO_LOGIT (INV_T / (QS4 * QS4))  // 2/4096, gemm logits

typedef __attribute__((ext_vector_type(2))) float floatx2;
typedef __attribute__((ext_vector_type(4))) float floatx4;
typedef __attribute__((ext_vector_type(16))) float floatx16;
typedef __attribute__((ext_vector_type(4))) int int4v;
typedef __attribute__((ext_vector_type(8))) int int8v;

static __device__ __forceinline__ void async_copy16(const void* g, void* lds) {
  __builtin_amdgcn_global_load_lds((const __attribute__((address_space(1))) void*)g,
                                   (__attribute__((address_space(3))) void*)lds,
                                   16, 0, 0);
}

// e2m1 encode of pre-scaled x: values {0,.5,1,1.5,2,3,4,6}, clamp at 6,
// round-to-nearest via midpoint thresholds. Returns 4-bit code.
static __device__ __forceinline__ unsigned int enc4(float x) {
  float u = fminf(fabsf(x), 6.0f);
  int c = (u >= 0.25f) + (u >= 0.75f) + (u >= 1.25f) + (u >= 1.75f) +
          (u >= 2.5f) + (u >= 3.5f) + (u >= 5.0f);
  return (unsigned)(c | (x < 0.f ? 8 : 0));
}

static __device__ __forceinline__ unsigned int pack8_fp4(
    const float4& v0, const float4& v1, float s) {
  return enc4(v0.x * s)        | (enc4(v0.y * s) << 4)  |
         (enc4(v0.z * s) << 8) | (enc4(v0.w * s) << 12) |
         (enc4(v1.x * s) << 16)| (enc4(v1.y * s) << 20) |
         (enc4(v1.z * s) << 24)| (enc4(v1.w * s) << 28);
}

// ---------------------------------------------------------------------------
// Kernel 0: zero s_a|s_b (4096 floats). Separate dispatch: K1's colsum
// atomics would race with same-kernel zeroing.
// ---------------------------------------------------------------------------
__global__ __launch_bounds__(256) void zero_kernel(float* z) {
  #pragma unroll
  for (int i = 0; i < 4; i++)
    *(floatx4*)&z[4 * (threadIdx.x + 256 * i)] = floatx4{0.f, 0.f, 0.f, 0.f};
}

// ---------------------------------------------------------------------------
// Kernel 1: per-row L2 normalize + fused f32 column sums.
// r15: REGISTER-PRESSURE fix. Evidence: normalize is ~40us invariant to TLP
// (r13), load pattern (r14), rows/block — and VGPR_Count=56 while the old
// structure needs 74+ live (acc[32]+v[32]+addr) => compiler was spilling /
// rematerializing in the hot loop (scratch round-trips: latency-serial,
// invisible in FETCH, invariant to everything tried). New structure makes
// spills impossible:
//  * one BLOCK per row: 256 threads x 8 elements. v0,v1 + acc[8] ~ 30 VGPR.
//  * thread t exclusively owns cols {4t..4t+3, 1024+4t..1024+4t+3} for the
//    whole block => NO LDS colsum combine; 8 direct atomics at the end
//    (2048/block x 512 blocks = 1M, same count as before).
//  * norm: wave shfl_xor + 4-float LDS exchange, ONE barrier per row
//    (double-buffered partials wpart[2][4] make one barrier sufficient).
//  * pack: 8 floats -> 8 nibbles -> ONE dword at q4[row*256+tid]
//    (1KB contiguous/block-instr). This is a (different) k-permutation of
//    the fp4 row — but a4 and c4 get the SAME permutation, and the gemm's
//    dot products are invariant under a shared k-permutation.
// mat 0 (source):     fp4 a4 + colsum -> s_a
// mat 1 (bc_target):  colsum -> s_b only
// mat 2 (raw_target): fp4 c4
// grid (256, 3), block 256, 16 rows/block.
// ---------------------------------------------------------------------------
__global__ __launch_bounds__(256) void normalize_colsum_kernel(
    const float* __restrict__ src, const float* __restrict__ bc,
    const float* __restrict__ raw,
    unsigned int* __restrict__ a4, unsigned int* __restrict__ c4,
    float* __restrict__ s_a, float* __restrict__ s_b) {
  const int mat = blockIdx.y;
  const int tid = threadIdx.x;
  const int wave = tid >> 6;
  const float* base = (mat == 0) ? src : ((mat == 1) ? bc : raw);
  unsigned int* q4 = (mat == 0) ? a4 : c4;  // unused for mat 1

  // acc[i] owns col 4*tid+i (i<4) and col 1024+4*tid+(i-4) (i>=4)
  float acc[8];
  #pragma unroll
  for (int i = 0; i < 8; i++) acc[i] = 0.f;

  __shared__ float wpart[2][4];  // double-buffered per-wave norm partials

  const int r0 = blockIdx.x * 16;
  #pragma unroll 2
  for (int r = 0; r < 16; r++) {
    const int row = r0 + r;
    const float4* rp = (const float4*)(base + (size_t)row * DD);
    const float4 v0 = rp[tid];        // cols 4t..4t+3      (4KB contiguous)
    const float4 v1 = rp[256 + tid];  // cols 1024+4t..     (4KB contiguous)
    float ss = v0.x * v0.x + v0.y * v0.y + v0.z * v0.z + v0.w * v0.w +
               v1.x * v1.x + v1.y * v1.y + v1.z * v1.z + v1.w * v1.w;
    #pragma unroll
    for (int off = 1; off < 64; off <<= 1) ss += __shfl_xor(ss, off, 64);
    if ((tid & 63) == 0) wpart[r & 1][wave] = ss;
    __syncthreads();
    // safe: row r's reads of wpart[r&1] complete before each thread reaches
    // barrier r+1, which precedes row r+2's overwrite of wpart[r&1].
    const float sinv = rsqrtf(wpart[r & 1][0] + wpart[r & 1][1] +
                              wpart[r & 1][2] + wpart[r & 1][3]);

    if (mat != 2) {  // f32 colsum accumulate (exact)
      acc[0] += v0.x * sinv; acc[1] += v0.y * sinv;
      acc[2] += v0.z * sinv; acc[3] += v0.w * sinv;
      acc[4] += v1.x * sinv; acc[5] += v1.y * sinv;
      acc[6] += v1.z * sinv; acc[7] += v1.w * sinv;
    }
    if (mat != 1) {  // fp4 pack: one dword per thread, coalesced
      q4[row * 256 + tid] = pack8_fp4(v0, v1, sinv * QS4);
    }
  }
  if (mat == 2) return;  // uniform per block

  float* dst = (mat == 0) ? s_a : s_b;
  #pragma unroll
  for (int i = 0; i < 4; i++) atomicAdd(&dst[4 * tid + i], acc[i]);
  #pragma unroll
  for (int i = 0; i < 4; i++) atomicAdd(&dst[1024 + 4 * tid + i], acc[4 + i]);
}

// ---------------------------------------------------------------------------
// Kernel 2: MX-fp4 MFMA GEMM a_n @ c_n^T with fused sum(exp(sim/T)) epilogue.
// UNCHANGED from r12/r14. (r15's fp4 k-permutation is shared by a4 and c4,
// so every dot product — and hence this kernel — is structurally identical.)
// Keeps: dbuf, XOR source-swizzle, bijective XCD-chunk swizzle, occupancy 2,
// 32x32x64 fp4 MFMA.
// grid (32, 32), block 256 (4 waves; each wave owns a 64x64 quadrant).
// ---------------------------------------------------------------------------
__global__ __launch_bounds__(256, 2) void gemm_expsum_kernel(
    const unsigned char* __restrict__ a4, const unsigned char* __restrict__ c4,
    float* __restrict__ S_part) {
  __shared__ unsigned char As[2][128 * 128];  // [buf][row][chunk^(row&7)]
  __shared__ unsigned char Cs[2][128 * 128];
  const int tid = threadIdx.x;
  const int lane = tid & 63;
  const int wave = tid >> 6;
  const int wr = wave >> 1;       // wave row quadrant (0/1)
  const int wc = wave & 1;        // wave col quadrant (0/1)
  const int half = lane >> 5;     // k-half selector within a k-step (K=64)
  const int l32 = lane & 31;

  // XCD-chunked swizzle (bijective: 1024 = 8 chunks x 128 blocks)
  const int lin = blockIdx.y * 32 + blockIdx.x;
  const int xcd = lin & 7;        // HW assigns lin -> XCD round-robin
  const int idx = lin >> 3;       // 0..127 within this XCD's chunk
  const int br = (xcd >> 1) * 8 + (idx >> 4);   // 4 chunk-rows of 8
  const int bc = (xcd & 1) * 16 + (idx & 15);   // 2 chunk-cols of 16

  floatx16 acc[2][2] = {};

  // staging: per matrix+buffer, 16 windows of 1KB (8 rows x 128B); 4/wave.
  // fp4 row = 1024B; ktile kt covers row bytes [kt*128, kt*128+128).
  const int wrow = lane >> 3;
  const int csrc = (lane & 7) ^ (wrow & 7);
  const unsigned char* gA[4];
  const unsigned char* gC[4];
  int ldsOff[4];
  #pragma unroll
  for (int q = 0; q < 4; q++) {
    const int m = wave * 4 + q;
    const int row = m * 8 + wrow;
    gA[q] = a4 + (size_t)(br * 128 + row) * 1024 + csrc * 16;
    gC[q] = c4 + (size_t)(bc * 128 + row) * 1024 + csrc * 16;
    ldsOff[q] = m * 1024;
  }

  // prologue: stage ktile 0 into buffer 0
  #pragma unroll
  for (int q = 0; q < 4; q++) {
    async_copy16(gA[q], &As[0][ldsOff[q]]);
    async_copy16(gC[q], &Cs[0][ldsOff[q]]);
    gA[q] += 128; gC[q] += 128;
  }

  const int NKT = DD / 256;  // 8 ktiles
  #pragma unroll 2
  for (int kt = 0; kt < NKT; kt++) {
    const int cur = kt & 1;
    __syncthreads();  // drains vmcnt: ktile-kt stage (issued one body ago)

    if (kt < NKT - 1) {  // prefetch kt+1 into the other buffer
      #pragma unroll
      for (int q = 0; q < 4; q++) {
        async_copy16(gA[q], &As[cur ^ 1][ldsOff[q]]);
        async_copy16(gC[q], &Cs[cur ^ 1][ldsOff[q]]);
        gA[q] += 128; gC[q] += 128;
      }
    }

    // fragments: k-step s (64 k-elems = 32B/row), lane(half,l32): 32 nibbles
    // = 16B at logical chunk s*2+half (physical ^(r&7)). fp4 uses v[0:3].
    int4v af[4][2], bf[4][2];
    #pragma unroll
    for (int s = 0; s < 4; s++) {
      #pragma unroll
      for (int i = 0; i < 2; i++) {
        const int r = wr * 64 + i * 32 + l32;
        const int pc = (s * 2 + half) ^ (r & 7);
        af[s][i] = *(const int4v*)&As[cur][r * 128 + pc * 16];
      }
      #pragma unroll
      for (int j = 0; j < 2; j++) {
        const int r = wc * 64 + j * 32 + l32;
        const int pc = (s * 2 + half) ^ (r & 7);
        bf[s][j] = *(const int4v*)&Cs[cur][r * 128 + pc * 16];
      }
    }
    #pragma unroll
    for (int s = 0; s < 4; s++)
      #pragma unroll
      for (int i = 0; i < 2; i++) {
        const int8v a8v = int8v{af[s][i][0], af[s][i][1], af[s][i][2],
                                af[s][i][3], 0, 0, 0, 0};
        #pragma unroll
        for (int j = 0; j < 2; j++) {
          const int8v b8v = int8v{bf[s][j][0], bf[s][j][1], bf[s][j][2],
                                  bf[s][j][3], 0, 0, 0, 0};
          acc[i][j] = __builtin_amdgcn_mfma_scale_f32_32x32x64_f8f6f4(
              a8v, b8v, acc[i][j], 4 /*cbsz: fp4*/, 4 /*blgp: fp4*/,
              0, 0x7F7F7F7F, 0, 0x7F7F7F7F /*E8M0 identity scales*/);
        }
      }
  }

  // epilogue: sum exp(sim/T) over this block's 128x128 tile; acc = 4096*sim.
  float local = 0.f;
  #pragma unroll
  for (int i = 0; i < 2; i++)
    #pragma unroll
    for (int j = 0; j < 2; j++)
      #pragma unroll
      for (int r = 0; r < 16; r++)
        local += __expf(acc[i][j][r] * ACC4_TO_LOGIT);
  #pragma unroll
  for (int off = 32; off > 0; off >>= 1) local += __shfl_down(local, off, 64);
  __shared__ float red[4];
  if (lane == 0) red[wave] = local;
  __syncthreads();
  if (tid == 0) S_part[br * 32 + bc] = red[0] + red[1] + red[2] + red[3];
}

// ---------------------------------------------------------------------------
// Kernel 3: tiny finalize. Separate dispatch => kernel-boundary coherence,
// so plain (non-atomic) reads of s_a/s_b/S_part are safe. 1 block.
// ---------------------------------------------------------------------------
__global__ __launch_bounds__(256) void finalize_kernel(
    const float* __restrict__ s_a, const float* __restrict__ s_b,
    const float* __restrict__ S_part, float* __restrict__ out) {
  const int tid = threadIdx.x;
  float dot = 0.f, se = 0.f;
  #pragma unroll
  for (int k = 0; k < 8; k++)
    dot += s_a[tid + 256 * k] * s_b[tid + 256 * k];
  #pragma unroll
  for (int k = 0; k < 4; k++) se += S_part[tid + 256 * k];
  #pragma unroll
  for (int off = 32; off > 0; off >>= 1) {
    dot += __shfl_down(dot, off, 64);
    se  += __shfl_down(se, off, 64);
  }
  __shared__ float redd[4], reds[4];
  if ((tid & 63) == 0) { redd[tid >> 6] = dot; reds[tid >> 6] = se; }
  __syncthreads();
  if (tid == 0) {
    const float dt = redd[0] + redd[1] + redd[2] + redd[3];
    const float st = reds[0] + reds[1] + reds[2] + reds[3];
    // loss = log(sum exp(sim_neg/T)) - mean(sim_pos)/T
    out[0] = logf(st) - dt * (INV_T / ((float)NR * (float)NR));
  }
}

extern "C" void kernel_launch(void* const* d_in, const int* in_sizes, int n_in,
                              void* d_out, int out_size, void* d_ws, size_t ws_size,
                              hipStream_t stream) {
  const float* src = (const float*)d_in[0];
  const float* bc  = (const float*)d_in[1];
  const float* raw = (const float*)d_in[2];

  char* ws = (char*)d_ws;
  unsigned int* a4 = (unsigned int*)ws;                             // 4 MiB
  unsigned int* c4 = (unsigned int*)(ws + (size_t)4 * 1024 * 1024); // 4 MiB
  float* zb  = (float*)(ws + (size_t)8 * 1024 * 1024);  // s_a | s_b (16 KiB)
  float* s_a = zb;
  float* s_b = zb + DD;
  float* S_part = (float*)(ws + (size_t)8 * 1024 * 1024 + 32 * 1024);  // 4 KiB

  zero_kernel<<<1, 256, 0, stream>>>(zb);
  normalize_colsum_kernel<<<dim3(NR / 16, 3), 256, 0, stream>>>(
      src, bc, raw, a4, c4, s_a, s_b);
  gemm_expsum_kernel<<<dim3(32, 32), 256, 0, stream>>>(
      (const unsigned char*)a4, (const unsigned char*)c4, S_part);
  finalize_kernel<<<1, 256, 0, stream>>>(s_a, s_b, S_part, (float*)d_out);
}

// Round 7
// 161.052 us; speedup vs baseline: 1.1835x; 1.1835x over previous
//
#include <hip/hip_runtime.h>

// Problem constants (N=4096 rows, D=2048 cols, T=0.5 -> 1/T = 2)
#define NR 4096
#define DD 2048
#define INV_T 2.0f
// fp4 path (gemm): a_n*64 ~ N(0,1.41) into e2m1 range ±6 (±4.2 sigma);
// MFMA acc = 4096*sim
#define QS4 64.0f
#define ACC4_TO_LOGIT (INV_T / (QS4 * QS4))  // 2/4096, gemm logits

typedef __attribute__((ext_vector_type(2))) float floatx2;
typedef __attribute__((ext_vector_type(4))) float floatx4;
typedef __attribute__((ext_vector_type(16))) float floatx16;
typedef __attribute__((ext_vector_type(4))) int int4v;
typedef __attribute__((ext_vector_type(8))) int int8v;
typedef __attribute__((ext_vector_type(4))) unsigned int uintx4;

static __device__ __forceinline__ void async_copy16(const void* g, void* lds) {
  __builtin_amdgcn_global_load_lds((const __attribute__((address_space(1))) void*)g,
                                   (__attribute__((address_space(3))) void*)lds,
                                   16, 0, 0);
}

// e2m1 encode of pre-scaled x: values {0,.5,1,1.5,2,3,4,6}, clamp at 6,
// round-to-nearest via midpoint thresholds. Returns 4-bit code.
static __device__ __forceinline__ unsigned int enc4(float x) {
  float u = fminf(fabsf(x), 6.0f);
  int c = (u >= 0.25f) + (u >= 0.75f) + (u >= 1.25f) + (u >= 1.75f) +
          (u >= 2.5f) + (u >= 3.5f) + (u >= 5.0f);
  return (unsigned)(c | (x < 0.f ? 8 : 0));
}

static __device__ __forceinline__ unsigned int pack8_fp4(
    const float4& v0, const float4& v1, float s) {
  return enc4(v0.x * s)        | (enc4(v0.y * s) << 4)  |
         (enc4(v0.z * s) << 8) | (enc4(v0.w * s) << 12) |
         (enc4(v1.x * s) << 16)| (enc4(v1.y * s) << 20) |
         (enc4(v1.z * s) << 24)| (enc4(v1.w * s) << 28);
}

// ---------------------------------------------------------------------------
// Kernel 1: per-row L2 normalize + fused f32 column sums.
// r16 = r14 core (wave-per-row, contiguous loads — the best measured
// structure; r15's block-per-row/barrier-per-row core regressed 40->70us and
// is reverted) with ONE change: the 1M device-scope colsum atomicAdds are
// replaced by plain per-block partial stores to part[mat][bx][2048].
// Rationale (ablation): normalize is ~40us invariant to TLP (r13), load
// pattern (r14), VGPR pressure (r15: VGPR 20, still slow) — the only
// structural constant across all variants is the 1M same-address atomics
// (4096 hot addresses); same-address f32 atomics serialize at the home TCC
// channel => O(10-30us) hidden cost, invisible in FETCH/VALU counters.
// This round removes them (and the zero_kernel, no longer needed).
// col mapping: acc[4c+i] <-> column 4*lane + 256*c + i (k-permuted fp4 pack
// is shared by a4/c4 => gemm dot products invariant).
// mat 0 (source):     fp4 a4 + col-partials -> part[0][bx]
// mat 1 (bc_target):  col-partials -> part[1][bx]
// mat 2 (raw_target): fp4 c4
// grid (256, 3), block 256, 16 rows/block (4/wave).
// ---------------------------------------------------------------------------
__global__ __launch_bounds__(256) void normalize_colsum_kernel(
    const float* __restrict__ src, const float* __restrict__ bc,
    const float* __restrict__ raw,
    unsigned int* __restrict__ a4, unsigned int* __restrict__ c4,
    float* __restrict__ part) {
  const int mat = blockIdx.y;
  const int tid = threadIdx.x;
  const int lane = tid & 63;
  const int wave = tid >> 6;
  const float* base = (mat == 0) ? src : ((mat == 1) ? bc : raw);
  unsigned int* q4 = (mat == 0) ? a4 : c4;  // unused for mat 1

  // acc[4c+i] accumulates column 4*lane + 256*c + i  (c<8, i<4)
  float acc[32];
  #pragma unroll
  for (int i = 0; i < 32; i++) acc[i] = 0.f;

  #pragma unroll
  for (int r = 0; r < 4; r++) {
    const int row = blockIdx.x * 16 + wave * 4 + r;
    const float4* rp = (const float4*)(base + (size_t)row * DD);
    float4 v[8];
    #pragma unroll
    for (int c = 0; c < 8; c++) v[c] = rp[lane + 64 * c];  // contiguous 1KB/instr
    float ss = 0.f;
    #pragma unroll
    for (int c = 0; c < 8; c++)
      ss += v[c].x * v[c].x + v[c].y * v[c].y + v[c].z * v[c].z + v[c].w * v[c].w;
    #pragma unroll
    for (int off = 1; off < 64; off <<= 1) ss += __shfl_xor(ss, off, 64);
    const float sinv = rsqrtf(ss);

    if (mat != 2) {  // f32 colsum accumulate (exact)
      #pragma unroll
      for (int c = 0; c < 8; c++) {
        acc[c * 4 + 0] += v[c].x * sinv; acc[c * 4 + 1] += v[c].y * sinv;
        acc[c * 4 + 2] += v[c].z * sinv; acc[c * 4 + 3] += v[c].w * sinv;
      }
    }
    if (mat != 1) {  // fp4 pack, permuted-k layout, one 16B store per lane
      const float s4 = sinv * QS4;
      uintx4 w;
      #pragma unroll
      for (int d = 0; d < 4; d++)
        w[d] = pack8_fp4(v[2 * d], v[2 * d + 1], s4);
      *(uintx4*)&q4[row * 256 + lane * 4] = w;
    }
  }
  if (mat == 2) return;  // uniform per block — no divergent barrier

  // cross-wave combine in LDS, then PLAIN coalesced partial store (no atomics)
  __shared__ float lsum[4][2048];
  #pragma unroll
  for (int c = 0; c < 8; c++)
    *(floatx4*)&lsum[wave][4 * lane + 256 * c] =
        floatx4{acc[4 * c], acc[4 * c + 1], acc[4 * c + 2], acc[4 * c + 3]};
  __syncthreads();
  float* dstp = part + ((size_t)mat * 256 + blockIdx.x) * 2048;
  #pragma unroll
  for (int k = 0; k < 8; k++) {
    const int col = tid + 256 * k;
    dstp[col] = lsum[0][col] + lsum[1][col] + lsum[2][col] + lsum[3][col];
  }
}

// ---------------------------------------------------------------------------
// Kernel 1b: column-partial reduce. s_a[col] = sum_bx part[0][bx][col];
// s_b likewise. 16 blocks x 256 threads; each block owns 256 cols of one
// mat and streams 256 L2-hot rows (1KB coalesced per step, 256KB total).
// Plain full-overwrite stores => no zero_kernel needed.
// ---------------------------------------------------------------------------
__global__ __launch_bounds__(256) void colreduce_kernel(
    const float* __restrict__ part, float* __restrict__ s_a,
    float* __restrict__ s_b) {
  const int mat = blockIdx.y;
  const int colbase = blockIdx.x * 256;
  const int tid = threadIdx.x;
  const float* p = part + (size_t)mat * 256 * 2048 + colbase;
  float acc = 0.f;
  #pragma unroll 8
  for (int b = 0; b < 256; b++) acc += p[(size_t)b * 2048 + tid];
  float* dst = (mat == 0) ? s_a : s_b;
  dst[colbase + tid] = acc;
}

// ---------------------------------------------------------------------------
// Kernel 2: MX-fp4 MFMA GEMM a_n @ c_n^T with fused sum(exp(sim/T)) epilogue.
// UNCHANGED from r12/r14 (single-variable discipline).
// Keeps: dbuf, XOR source-swizzle, bijective XCD-chunk swizzle, occupancy 2,
// 32x32x64 fp4 MFMA.
// grid (32, 32), block 256 (4 waves; each wave owns a 64x64 quadrant).
// ---------------------------------------------------------------------------
__global__ __launch_bounds__(256, 2) void gemm_expsum_kernel(
    const unsigned char* __restrict__ a4, const unsigned char* __restrict__ c4,
    float* __restrict__ S_part) {
  __shared__ unsigned char As[2][128 * 128];  // [buf][row][chunk^(row&7)]
  __shared__ unsigned char Cs[2][128 * 128];
  const int tid = threadIdx.x;
  const int lane = tid & 63;
  const int wave = tid >> 6;
  const int wr = wave >> 1;       // wave row quadrant (0/1)
  const int wc = wave & 1;        // wave col quadrant (0/1)
  const int half = lane >> 5;     // k-half selector within a k-step (K=64)
  const int l32 = lane & 31;

  // XCD-chunked swizzle (bijective: 1024 = 8 chunks x 128 blocks)
  const int lin = blockIdx.y * 32 + blockIdx.x;
  const int xcd = lin & 7;        // HW assigns lin -> XCD round-robin
  const int idx = lin >> 3;       // 0..127 within this XCD's chunk
  const int br = (xcd >> 1) * 8 + (idx >> 4);   // 4 chunk-rows of 8
  const int bc = (xcd & 1) * 16 + (idx & 15);   // 2 chunk-cols of 16

  floatx16 acc[2][2] = {};

  // staging: per matrix+buffer, 16 windows of 1KB (8 rows x 128B); 4/wave.
  // fp4 row = 1024B; ktile kt covers row bytes [kt*128, kt*128+128).
  const int wrow = lane >> 3;
  const int csrc = (lane & 7) ^ (wrow & 7);
  const unsigned char* gA[4];
  const unsigned char* gC[4];
  int ldsOff[4];
  #pragma unroll
  for (int q = 0; q < 4; q++) {
    const int m = wave * 4 + q;
    const int row = m * 8 + wrow;
    gA[q] = a4 + (size_t)(br * 128 + row) * 1024 + csrc * 16;
    gC[q] = c4 + (size_t)(bc * 128 + row) * 1024 + csrc * 16;
    ldsOff[q] = m * 1024;
  }

  // prologue: stage ktile 0 into buffer 0
  #pragma unroll
  for (int q = 0; q < 4; q++) {
    async_copy16(gA[q], &As[0][ldsOff[q]]);
    async_copy16(gC[q], &Cs[0][ldsOff[q]]);
    gA[q] += 128; gC[q] += 128;
  }

  const int NKT = DD / 256;  // 8 ktiles
  #pragma unroll 2
  for (int kt = 0; kt < NKT; kt++) {
    const int cur = kt & 1;
    __syncthreads();  // drains vmcnt: ktile-kt stage (issued one body ago)

    if (kt < NKT - 1) {  // prefetch kt+1 into the other buffer
      #pragma unroll
      for (int q = 0; q < 4; q++) {
        async_copy16(gA[q], &As[cur ^ 1][ldsOff[q]]);
        async_copy16(gC[q], &Cs[cur ^ 1][ldsOff[q]]);
        gA[q] += 128; gC[q] += 128;
      }
    }

    // fragments: k-step s (64 k-elems = 32B/row), lane(half,l32): 32 nibbles
    // = 16B at logical chunk s*2+half (physical ^(r&7)). fp4 uses v[0:3].
    int4v af[4][2], bf[4][2];
    #pragma unroll
    for (int s = 0; s < 4; s++) {
      #pragma unroll
      for (int i = 0; i < 2; i++) {
        const int r = wr * 64 + i * 32 + l32;
        const int pc = (s * 2 + half) ^ (r & 7);
        af[s][i] = *(const int4v*)&As[cur][r * 128 + pc * 16];
      }
      #pragma unroll
      for (int j = 0; j < 2; j++) {
        const int r = wc * 64 + j * 32 + l32;
        const int pc = (s * 2 + half) ^ (r & 7);
        bf[s][j] = *(const int4v*)&Cs[cur][r * 128 + pc * 16];
      }
    }
    #pragma unroll
    for (int s = 0; s < 4; s++)
      #pragma unroll
      for (int i = 0; i < 2; i++) {
        const int8v a8v = int8v{af[s][i][0], af[s][i][1], af[s][i][2],
                                af[s][i][3], 0, 0, 0, 0};
        #pragma unroll
        for (int j = 0; j < 2; j++) {
          const int8v b8v = int8v{bf[s][j][0], bf[s][j][1], bf[s][j][2],
                                  bf[s][j][3], 0, 0, 0, 0};
          acc[i][j] = __builtin_amdgcn_mfma_scale_f32_32x32x64_f8f6f4(
              a8v, b8v, acc[i][j], 4 /*cbsz: fp4*/, 4 /*blgp: fp4*/,
              0, 0x7F7F7F7F, 0, 0x7F7F7F7F /*E8M0 identity scales*/);
        }
      }
  }

  // epilogue: sum exp(sim/T) over this block's 128x128 tile; acc = 4096*sim.
  float local = 0.f;
  #pragma unroll
  for (int i = 0; i < 2; i++)
    #pragma unroll
    for (int j = 0; j < 2; j++)
      #pragma unroll
      for (int r = 0; r < 16; r++)
        local += __expf(acc[i][j][r] * ACC4_TO_LOGIT);
  #pragma unroll
  for (int off = 32; off > 0; off >>= 1) local += __shfl_down(local, off, 64);
  __shared__ float red[4];
  if (lane == 0) red[wave] = local;
  __syncthreads();
  if (tid == 0) S_part[br * 32 + bc] = red[0] + red[1] + red[2] + red[3];
}

// ---------------------------------------------------------------------------
// Kernel 3: tiny finalize. Separate dispatch => kernel-boundary coherence,
// so plain (non-atomic) reads of s_a/s_b/S_part are safe. 1 block.
// ---------------------------------------------------------------------------
__global__ __launch_bounds__(256) void finalize_kernel(
    const float* __restrict__ s_a, const float* __restrict__ s_b,
    const float* __restrict__ S_part, float* __restrict__ out) {
  const int tid = threadIdx.x;
  float dot = 0.f, se = 0.f;
  #pragma unroll
  for (int k = 0; k < 8; k++)
    dot += s_a[tid + 256 * k] * s_b[tid + 256 * k];
  #pragma unroll
  for (int k = 0; k < 4; k++) se += S_part[tid + 256 * k];
  #pragma unroll
  for (int off = 32; off > 0; off >>= 1) {
    dot += __shfl_down(dot, off, 64);
    se  += __shfl_down(se, off, 64);
  }
  __shared__ float redd[4], reds[4];
  if ((tid & 63) == 0) { redd[tid >> 6] = dot; reds[tid >> 6] = se; }
  __syncthreads();
  if (tid == 0) {
    const float dt = redd[0] + redd[1] + redd[2] + redd[3];
    const float st = reds[0] + reds[1] + reds[2] + reds[3];
    // loss = log(sum exp(sim_neg/T)) - mean(sim_pos)/T
    out[0] = logf(st) - dt * (INV_T / ((float)NR * (float)NR));
  }
}

extern "C" void kernel_launch(void* const* d_in, const int* in_sizes, int n_in,
                              void* d_out, int out_size, void* d_ws, size_t ws_size,
                              hipStream_t stream) {
  const float* src = (const float*)d_in[0];
  const float* bc  = (const float*)d_in[1];
  const float* raw = (const float*)d_in[2];

  char* ws = (char*)d_ws;
  unsigned int* a4 = (unsigned int*)ws;                              // 4 MiB
  unsigned int* c4 = (unsigned int*)(ws + (size_t)4 * 1024 * 1024);  // 4 MiB
  float* part = (float*)(ws + (size_t)8 * 1024 * 1024);              // 4 MiB
  float* zb   = (float*)(ws + (size_t)12 * 1024 * 1024);  // s_a | s_b (16 KiB)
  float* s_a  = zb;
  float* s_b  = zb + DD;
  float* S_part = (float*)(ws + (size_t)12 * 1024 * 1024 + 32 * 1024);  // 4 KiB

  normalize_colsum_kernel<<<dim3(NR / 16, 3), 256, 0, stream>>>(
      src, bc, raw, a4, c4, part);
  colreduce_kernel<<<dim3(8, 2), 256, 0, stream>>>(part, s_a, s_b);
  gemm_expsum_kernel<<<dim3(32, 32), 256, 0, stream>>>(
      (const unsigned char*)a4, (const unsigned char*)c4, S_part);
  finalize_kernel<<<1, 256, 0, stream>>>(s_a, s_b, S_part, (float*)d_out);
}

// Round 10
// 154.613 us; speedup vs baseline: 1.2328x; 1.0416x over previous
//
#include <hip/hip_runtime.h>

// Problem constants (N=4096 rows, D=2048 cols, T=0.5 -> 1/T = 2)
#define NR 4096
#define DD 2048
#define INV_T 2.0f
// fp4 path (gemm): a_n*64 ~ N(0,1.41) into e2m1 range ±6 (±4.2 sigma);
// MFMA acc = 4096*sim
#define QS4 64.0f
#define ACC4_TO_LOGIT (INV_T / (QS4 * QS4))  // 2/4096, gemm logits

typedef __attribute__((ext_vector_type(2))) float floatx2;
typedef __attribute__((ext_vector_type(4))) float floatx4;
typedef __attribute__((ext_vector_type(16))) float floatx16;
typedef __attribute__((ext_vector_type(4))) int int4v;
typedef __attribute__((ext_vector_type(8))) int int8v;
typedef __attribute__((ext_vector_type(4))) unsigned int uintx4;

static __device__ __forceinline__ void async_copy16(const void* g, void* lds) {
  __builtin_amdgcn_global_load_lds((const __attribute__((address_space(1))) void*)g,
                                   (__attribute__((address_space(3))) void*)lds,
                                   16, 0, 0);
}

// e2m1 encode of pre-scaled x: values {0,.5,1,1.5,2,3,4,6}, clamp at 6,
// round-to-nearest via midpoint thresholds. Returns 4-bit code.
static __device__ __forceinline__ unsigned int enc4(float x) {
  float u = fminf(fabsf(x), 6.0f);
  int c = (u >= 0.25f) + (u >= 0.75f) + (u >= 1.25f) + (u >= 1.75f) +
          (u >= 2.5f) + (u >= 3.5f) + (u >= 5.0f);
  return (unsigned)(c | (x < 0.f ? 8 : 0));
}

static __device__ __forceinline__ unsigned int pack8_fp4(
    const float4& v0, const float4& v1, float s) {
  return enc4(v0.x * s)        | (enc4(v0.y * s) << 4)  |
         (enc4(v0.z * s) << 8) | (enc4(v0.w * s) << 12) |
         (enc4(v1.x * s) << 16)| (enc4(v1.y * s) << 20) |
         (enc4(v1.z * s) << 24)| (enc4(v1.w * s) << 28);
}

// ---------------------------------------------------------------------------
// Kernel 0: zero s_a|s_b (4096 floats). Separate dispatch: K1's colsum
// atomics would race with same-kernel zeroing.
// ---------------------------------------------------------------------------
__global__ __launch_bounds__(256) void zero_kernel(float* z) {
  #pragma unroll
  for (int i = 0; i < 4; i++)
    *(floatx4*)&z[4 * (threadIdx.x + 256 * i)] = floatx4{0.f, 0.f, 0.f, 0.f};
}

// ---------------------------------------------------------------------------
// Kernel 1: per-row L2 normalize + fused f32 column sums.
// r19 (= r17 resubmit; rounds 8/9 were infra failures, never ran. One
// hardening: the opaque-CSE-blocker is now a 32-bit zero offset instead of
// a 64-bit "+v" pointer constraint — avoids any VGPR-pair asm edge case).
// TWO-PASS row processing (theory #5: hidden spill/reload).
// Evidence: the r14 structure's live set across the shfl-reduce is
// >= 64 VGPR (v[32] needed after the reduce + acc[32] loop-carried), but
// VGPR_Count=56 => the compiler was spilling or re-loading on its own
// terms; that serialized cost is invisible in every counter and invariant
// to TLP/pattern/atomics — matching 4 rounds of null results.
// Fix: make the re-read explicit and cheap:
//   pass 1: stream the row, accumulate ss only (each float4 dies at once).
//   shfl_xor reduce -> sinv (no barriers, wave-per-row).
//   pass 2: RE-LOAD the row via an opaque offset (asm blocks CSE, so these
//     are real loads — but L1/L2-hot: 12 waves/CU x 8KB = 3MB/XCD).
//     Only 2 transient float4 + acc[32] live => ~45 VGPR, spill-free.
// Colsum sink: r12's proven LDS-combine + 2048 atomics/block (r16's
// part-store+colreduce alternative measured WORSE: 161 vs 148).
// mat 0 (source):     fp4 a4 + colsum -> s_a
// mat 1 (bc_target):  colsum -> s_b only
// mat 2 (raw_target): fp4 c4
// col mapping: acc[4c+i] <-> column 4*lane + 256*c + i; fp4 pack order is a
// k-permutation shared by a4/c4 => gemm dot products invariant.
// grid (256, 3), block 256, 16 rows/block (4/wave).
// ---------------------------------------------------------------------------
__global__ __launch_bounds__(256) void normalize_colsum_kernel(
    const float* __restrict__ src, const float* __restrict__ bc,
    const float* __restrict__ raw,
    unsigned int* __restrict__ a4, unsigned int* __restrict__ c4,
    float* __restrict__ s_a, float* __restrict__ s_b) {
  const int mat = blockIdx.y;
  const int tid = threadIdx.x;
  const int lane = tid & 63;
  const int wave = tid >> 6;
  const float* base = (mat == 0) ? src : ((mat == 1) ? bc : raw);
  unsigned int* q4 = (mat == 0) ? a4 : c4;  // unused for mat 1

  // acc[4c+i] accumulates column 4*lane + 256*c + i  (c<8, i<4)
  float acc[32];
  #pragma unroll
  for (int i = 0; i < 32; i++) acc[i] = 0.f;

  #pragma unroll
  for (int r = 0; r < 4; r++) {
    const int row = blockIdx.x * 16 + wave * 4 + r;
    const float4* rp = (const float4*)(base + (size_t)row * DD);

    // pass 1: sum of squares; loads die immediately (~10 live VGPRs)
    float ss = 0.f;
    #pragma unroll
    for (int c = 0; c < 8; c++) {
      const float4 v = rp[lane + 64 * c];
      ss += v.x * v.x + v.y * v.y + v.z * v.z + v.w * v.w;
    }
    #pragma unroll
    for (int off = 1; off < 64; off <<= 1) ss += __shfl_xor(ss, off, 64);
    const float sinv = rsqrtf(ss);

    // opaque zero offset: forces pass-2 loads to be real (L1/L2-hot)
    // re-reads instead of the compiler keeping 32 floats live across the
    // reduce. 32-bit => single-VGPR asm constraint, no pair edge case.
    int zoff = 0;
    asm volatile("" : "+v"(zoff));
    const float4* rp2 = rp + zoff;

    if (mat == 1) {  // colsum only
      #pragma unroll
      for (int c = 0; c < 8; c++) {
        const float4 v = rp2[lane + 64 * c];
        acc[c * 4 + 0] += v.x * sinv; acc[c * 4 + 1] += v.y * sinv;
        acc[c * 4 + 2] += v.z * sinv; acc[c * 4 + 3] += v.w * sinv;
      }
    } else {  // pack (+ colsum for mat 0)
      const float s4 = sinv * QS4;
      uintx4 w;
      #pragma unroll
      for (int d = 0; d < 4; d++) {
        const float4 f0 = rp2[lane + 128 * d];       // c = 2d
        const float4 f1 = rp2[lane + 64 + 128 * d];  // c = 2d+1
        if (mat == 0) {
          acc[8 * d + 0] += f0.x * sinv; acc[8 * d + 1] += f0.y * sinv;
          acc[8 * d + 2] += f0.z * sinv; acc[8 * d + 3] += f0.w * sinv;
          acc[8 * d + 4] += f1.x * sinv; acc[8 * d + 5] += f1.y * sinv;
          acc[8 * d + 6] += f1.z * sinv; acc[8 * d + 7] += f1.w * sinv;
        }
        w[d] = pack8_fp4(f0, f1, s4);
      }
      *(uintx4*)&q4[row * 256 + lane * 4] = w;  // 16B/lane, 1KB/wave
    }
  }
  if (mat == 2) return;  // uniform per block — no divergent barrier

  // cross-wave combine, then one device atomic per column per block.
  __shared__ float lsum[4][2048];
  #pragma unroll
  for (int c = 0; c < 8; c++)
    *(floatx4*)&lsum[wave][4 * lane + 256 * c] =
        floatx4{acc[4 * c], acc[4 * c + 1], acc[4 * c + 2], acc[4 * c + 3]};
  __syncthreads();
  float* dst = (mat == 0) ? s_a : s_b;
  #pragma unroll
  for (int k = 0; k < 8; k++) {
    const int col = tid + 256 * k;
    atomicAdd(&dst[col],
              lsum[0][col] + lsum[1][col] + lsum[2][col] + lsum[3][col]);
  }
}

// ---------------------------------------------------------------------------
// Kernel 2: MX-fp4 MFMA GEMM a_n @ c_n^T with fused sum(exp(sim/T)) epilogue.
// UNCHANGED from r12 (single-variable discipline).
// Keeps: dbuf, XOR source-swizzle, bijective XCD-chunk swizzle, occupancy 2,
// 32x32x64 fp4 MFMA.
// grid (32, 32), block 256 (4 waves; each wave owns a 64x64 quadrant).
// ---------------------------------------------------------------------------
__global__ __launch_bounds__(256, 2) void gemm_expsum_kernel(
    const unsigned char* __restrict__ a4, const unsigned char* __restrict__ c4,
    float* __restrict__ S_part) {
  __shared__ unsigned char As[2][128 * 128];  // [buf][row][chunk^(row&7)]
  __shared__ unsigned char Cs[2][128 * 128];
  const int tid = threadIdx.x;
  const int lane = tid & 63;
  const int wave = tid >> 6;
  const int wr = wave >> 1;       // wave row quadrant (0/1)
  const int wc = wave & 1;        // wave col quadrant (0/1)
  const int half = lane >> 5;     // k-half selector within a k-step (K=64)
  const int l32 = lane & 31;

  // XCD-chunked swizzle (bijective: 1024 = 8 chunks x 128 blocks)
  const int lin = blockIdx.y * 32 + blockIdx.x;
  const int xcd = lin & 7;        // HW assigns lin -> XCD round-robin
  const int idx = lin >> 3;       // 0..127 within this XCD's chunk
  const int br = (xcd >> 1) * 8 + (idx >> 4);   // 4 chunk-rows of 8
  const int bc = (xcd & 1) * 16 + (idx & 15);   // 2 chunk-cols of 16

  floatx16 acc[2][2] = {};

  // staging: per matrix+buffer, 16 windows of 1KB (8 rows x 128B); 4/wave.
  // fp4 row = 1024B; ktile kt covers row bytes [kt*128, kt*128+128).
  const int wrow = lane >> 3;
  const int csrc = (lane & 7) ^ (wrow & 7);
  const unsigned char* gA[4];
  const unsigned char* gC[4];
  int ldsOff[4];
  #pragma unroll
  for (int q = 0; q < 4; q++) {
    const int m = wave * 4 + q;
    const int row = m * 8 + wrow;
    gA[q] = a4 + (size_t)(br * 128 + row) * 1024 + csrc * 16;
    gC[q] = c4 + (size_t)(bc * 128 + row) * 1024 + csrc * 16;
    ldsOff[q] = m * 1024;
  }

  // prologue: stage ktile 0 into buffer 0
  #pragma unroll
  for (int q = 0; q < 4; q++) {
    async_copy16(gA[q], &As[0][ldsOff[q]]);
    async_copy16(gC[q], &Cs[0][ldsOff[q]]);
    gA[q] += 128; gC[q] += 128;
  }

  const int NKT = DD / 256;  // 8 ktiles
  #pragma unroll 2
  for (int kt = 0; kt < NKT; kt++) {
    const int cur = kt & 1;
    __syncthreads();  // drains vmcnt: ktile-kt stage (issued one body ago)

    if (kt < NKT - 1) {  // prefetch kt+1 into the other buffer
      #pragma unroll
      for (int q = 0; q < 4; q++) {
        async_copy16(gA[q], &As[cur ^ 1][ldsOff[q]]);
        async_copy16(gC[q], &Cs[cur ^ 1][ldsOff[q]]);
        gA[q] += 128; gC[q] += 128;
      }
    }

    // fragments: k-step s (64 k-elems = 32B/row), lane(half,l32): 32 nibbles
    // = 16B at logical chunk s*2+half (physical ^(r&7)). fp4 uses v[0:3].
    int4v af[4][2], bf[4][2];
    #pragma unroll
    for (int s = 0; s < 4; s++) {
      #pragma unroll
      for (int i = 0; i < 2; i++) {
        const int r = wr * 64 + i * 32 + l32;
        const int pc = (s * 2 + half) ^ (r & 7);
        af[s][i] = *(const int4v*)&As[cur][r * 128 + pc * 16];
      }
      #pragma unroll
      for (int j = 0; j < 2; j++) {
        const int r = wc * 64 + j * 32 + l32;
        const int pc = (s * 2 + half) ^ (r & 7);
        bf[s][j] = *(const int4v*)&Cs[cur][r * 128 + pc * 16];
      }
    }
    #pragma unroll
    for (int s = 0; s < 4; s++)
      #pragma unroll
      for (int i = 0; i < 2; i++) {
        const int8v a8v = int8v{af[s][i][0], af[s][i][1], af[s][i][2],
                                af[s][i][3], 0, 0, 0, 0};
        #pragma unroll
        for (int j = 0; j < 2; j++) {
          const int8v b8v = int8v{bf[s][j][0], bf[s][j][1], bf[s][j][2],
                                  bf[s][j][3], 0, 0, 0, 0};
          acc[i][j] = __builtin_amdgcn_mfma_scale_f32_32x32x64_f8f6f4(
              a8v, b8v, acc[i][j], 4 /*cbsz: fp4*/, 4 /*blgp: fp4*/,
              0, 0x7F7F7F7F, 0, 0x7F7F7F7F /*E8M0 identity scales*/);
        }
      }
  }

  // epilogue: sum exp(sim/T) over this block's 128x128 tile; acc = 4096*sim.
  float local = 0.f;
  #pragma unroll
  for (int i = 0; i < 2; i++)
    #pragma unroll
    for (int j = 0; j < 2; j++)
      #pragma unroll
      for (int r = 0; r < 16; r++)
        local += __expf(acc[i][j][r] * ACC4_TO_LOGIT);
  #pragma unroll
  for (int off = 32; off > 0; off >>= 1) local += __shfl_down(local, off, 64);
  __shared__ float red[4];
  if (lane == 0) red[wave] = local;
  __syncthreads();
  if (tid == 0) S_part[br * 32 + bc] = red[0] + red[1] + red[2] + red[3];
}

// ---------------------------------------------------------------------------
// Kernel 3: tiny finalize. Separate dispatch => kernel-boundary coherence,
// so plain (non-atomic) reads of s_a/s_b/S_part are safe. 1 block.
// ---------------------------------------------------------------------------
__global__ __launch_bounds__(256) void finalize_kernel(
    const float* __restrict__ s_a, const float* __restrict__ s_b,
    const float* __restrict__ S_part, float* __restrict__ out) {
  const int tid = threadIdx.x;
  float dot = 0.f, se = 0.f;
  #pragma unroll
  for (int k = 0; k < 8; k++)
    dot += s_a[tid + 256 * k] * s_b[tid + 256 * k];
  #pragma unroll
  for (int k = 0; k < 4; k++) se += S_part[tid + 256 * k];
  #pragma unroll
  for (int off = 32; off > 0; off >>= 1) {
    dot += __shfl_down(dot, off, 64);
    se  += __shfl_down(se, off, 64);
  }
  __shared__ float redd[4], reds[4];
  if ((tid & 63) == 0) { redd[tid >> 6] = dot; reds[tid >> 6] = se; }
  __syncthreads();
  if (tid == 0) {
    const float dt = redd[0] + redd[1] + redd[2] + redd[3];
    const float st = reds[0] + reds[1] + reds[2] + reds[3];
    // loss = log(sum exp(sim_neg/T)) - mean(sim_pos)/T
    out[0] = logf(st) - dt * (INV_T / ((float)NR * (float)NR));
  }
}

extern "C" void kernel_launch(void* const* d_in, const int* in_sizes, int n_in,
                              void* d_out, int out_size, void* d_ws, size_t ws_size,
                              hipStream_t stream) {
  const float* src = (const float*)d_in[0];
  const float* bc  = (const float*)d_in[1];
  const float* raw = (const float*)d_in[2];

  char* ws = (char*)d_ws;
  unsigned int* a4 = (unsigned int*)ws;                             // 4 MiB
  unsigned int* c4 = (unsigned int*)(ws + (size_t)4 * 1024 * 1024); // 4 MiB
  float* zb  = (float*)(ws + (size_t)8 * 1024 * 1024);  // s_a | s_b (16 KiB)
  float* s_a = zb;
  float* s_b = zb + DD;
  float* S_part = (float*)(ws + (size_t)8 * 1024 * 1024 + 32 * 1024);  // 4 KiB

  zero_kernel<<<1, 256, 0, stream>>>(zb);
  normalize_colsum_kernel<<<dim3(NR / 16, 3), 256, 0, stream>>>(
      src, bc, raw, a4, c4, s_a, s_b);
  gemm_expsum_kernel<<<dim3(32, 32), 256, 0, stream>>>(
      (const unsigned char*)a4, (const unsigned char*)c4, S_part);
  finalize_kernel<<<1, 256, 0, stream>>>(s_a, s_b, S_part, (float*)d_out);
}

// Round 11
// 151.495 us; speedup vs baseline: 1.2581x; 1.0206x over previous
//
#include <hip/hip_runtime.h>

// Problem constants (N=4096 rows, D=2048 cols, T=0.5 -> 1/T = 2)
#define NR 4096
#define DD 2048
#define INV_T 2.0f
// fp4 path (gemm): a_n*64 ~ N(0,1.41) into e2m1 range ±6 (±4.2 sigma);
// MFMA acc = 4096*sim
#define QS4 64.0f
#define ACC4_TO_LOGIT (INV_T / (QS4 * QS4))  // 2/4096, gemm logits

typedef __attribute__((ext_vector_type(2))) float floatx2;
typedef __attribute__((ext_vector_type(4))) float floatx4;
typedef __attribute__((ext_vector_type(16))) float floatx16;
typedef __attribute__((ext_vector_type(4))) int int4v;
typedef __attribute__((ext_vector_type(8))) int int8v;
typedef __attribute__((ext_vector_type(4))) unsigned int uintx4;

static __device__ __forceinline__ void async_copy16(const void* g, void* lds) {
  __builtin_amdgcn_global_load_lds((const __attribute__((address_space(1))) void*)g,
                                   (__attribute__((address_space(3))) void*)lds,
                                   16, 0, 0);
}

// e2m1 encode of pre-scaled x: values {0,.5,1,1.5,2,3,4,6}, clamp at 6,
// round-to-nearest via midpoint thresholds. Returns 4-bit code.
static __device__ __forceinline__ unsigned int enc4(float x) {
  float u = fminf(fabsf(x), 6.0f);
  int c = (u >= 0.25f) + (u >= 0.75f) + (u >= 1.25f) + (u >= 1.75f) +
          (u >= 2.5f) + (u >= 3.5f) + (u >= 5.0f);
  return (unsigned)(c | (x < 0.f ? 8 : 0));
}

// r20: HW fp4 pack when available — 4 cvt instrs replace ~110 threshold ops.
// v_cvt_scalef32_pk_fp4_f32(old, s0, s1, scale, byte_sel): writes fp4(s0)
// into the low nibble and fp4(s1) into the high nibble of byte byte_sel.
// scale=1.0f => identity scaling; RNE; saturates to ±6 (same as enc4 clamp).
#if __has_builtin(__builtin_amdgcn_cvt_scalef32_pk_fp4_f32)
#define HW_FP4 1
static __device__ __forceinline__ unsigned int pack8_fp4(
    const float4& v0, const float4& v1, float s) {
  unsigned int w = 0;
  w = __builtin_amdgcn_cvt_scalef32_pk_fp4_f32(w, v0.x * s, v0.y * s, 1.0f, 0);
  w = __builtin_amdgcn_cvt_scalef32_pk_fp4_f32(w, v0.z * s, v0.w * s, 1.0f, 1);
  w = __builtin_amdgcn_cvt_scalef32_pk_fp4_f32(w, v1.x * s, v1.y * s, 1.0f, 2);
  w = __builtin_amdgcn_cvt_scalef32_pk_fp4_f32(w, v1.z * s, v1.w * s, 1.0f, 3);
  return w;
}
#else
static __device__ __forceinline__ unsigned int pack8_fp4(
    const float4& v0, const float4& v1, float s) {
  return enc4(v0.x * s)        | (enc4(v0.y * s) << 4)  |
         (enc4(v0.z * s) << 8) | (enc4(v0.w * s) << 12) |
         (enc4(v1.x * s) << 16)| (enc4(v1.y * s) << 20) |
         (enc4(v1.z * s) << 24)| (enc4(v1.w * s) << 28);
}
#endif

// ---------------------------------------------------------------------------
// Kernel 0: zero s_a|s_b (4096 floats). Separate dispatch: K1's colsum
// atomics would race with same-kernel zeroing.
// ---------------------------------------------------------------------------
__global__ __launch_bounds__(256) void zero_kernel(float* z) {
  #pragma unroll
  for (int i = 0; i < 4; i++)
    *(floatx4*)&z[4 * (threadIdx.x + 256 * i)] = floatx4{0.f, 0.f, 0.f, 0.f};
}

// ---------------------------------------------------------------------------
// Kernel 1: per-row L2 normalize + fused f32 column sums.
// r20: CODE-FOOTPRINT fix (theory #6: instruction-fetch bound).
// Evidence: normalize ~41us invariant to TLP (r13), access pattern (r14),
// VGPR pressure (r19, real two-pass), atomics (r16); logical reads DOUBLED
// in r19 with zero time change; VALU-throughput math says ~5-9us and memory
// ~18us — neither binds. The one constant: ~25-30KB of unrolled code
// (4 rows x ~700 instrs of threshold-chain enc4) ~ I$ size. Front-end
// stalls show as all-pipes-idle and are invariant to every data-side knob.
// Fix (shrinks code ~10x, keeps load ILP):
//  * HW fp4 cvt (see pack8_fp4 above): pack 450 -> ~50 instrs/row.
//  * row loop ROLLED (#pragma unroll 1): 4x less code; within-row loops
//    stay unrolled so the 8 pass-1 loads issue in parallel (r15 lesson:
//    never serialize the loads).
//  * two-pass structure kept from r19 (proven spill-free, ~equal perf).
// Colsum sink: r12's LDS-combine + 2048 atomics/block (best total measured).
// mat 0: fp4 a4 + colsum->s_a | mat 1: colsum->s_b | mat 2: fp4 c4.
// col mapping: acc[4c+i] <-> column 4*lane + 256*c + i; fp4 pack order is a
// k-permutation shared by a4/c4 => gemm dot products invariant.
// grid (256, 3), block 256, 16 rows/block (4/wave).
// ---------------------------------------------------------------------------
__global__ __launch_bounds__(256) void normalize_colsum_kernel(
    const float* __restrict__ src, const float* __restrict__ bc,
    const float* __restrict__ raw,
    unsigned int* __restrict__ a4, unsigned int* __restrict__ c4,
    float* __restrict__ s_a, float* __restrict__ s_b) {
  const int mat = blockIdx.y;
  const int tid = threadIdx.x;
  const int lane = tid & 63;
  const int wave = tid >> 6;
  const float* base = (mat == 0) ? src : ((mat == 1) ? bc : raw);
  unsigned int* q4 = (mat == 0) ? a4 : c4;  // unused for mat 1

  // acc[4c+i] accumulates column 4*lane + 256*c + i  (c<8, i<4)
  float acc[32];
  #pragma unroll
  for (int i = 0; i < 32; i++) acc[i] = 0.f;

  #pragma unroll 1   // rolled: 4x smaller I-footprint (the point of r20)
  for (int r = 0; r < 4; r++) {
    const int row = blockIdx.x * 16 + wave * 4 + r;
    const float4* rp = (const float4*)(base + (size_t)row * DD);

    // pass 1: sum of squares; 8 independent loads issue in parallel
    float ss = 0.f;
    #pragma unroll
    for (int c = 0; c < 8; c++) {
      const float4 v = rp[lane + 64 * c];
      ss += v.x * v.x + v.y * v.y + v.z * v.z + v.w * v.w;
    }
    #pragma unroll
    for (int off = 1; off < 64; off <<= 1) ss += __shfl_xor(ss, off, 64);
    const float sinv = rsqrtf(ss);

    // opaque zero offset: pass-2 loads are real (L1/L2-hot) re-reads, so
    // only acc[32] + 2 float4s are live across the reduce (no spills).
    int zoff = 0;
    asm volatile("" : "+v"(zoff));
    const float4* rp2 = rp + zoff;

    if (mat == 1) {  // colsum only
      #pragma unroll
      for (int c = 0; c < 8; c++) {
        const float4 v = rp2[lane + 64 * c];
        acc[c * 4 + 0] += v.x * sinv; acc[c * 4 + 1] += v.y * sinv;
        acc[c * 4 + 2] += v.z * sinv; acc[c * 4 + 3] += v.w * sinv;
      }
    } else {  // pack (+ colsum for mat 0)
      const float s4 = sinv * QS4;
      uintx4 w;
      #pragma unroll
      for (int d = 0; d < 4; d++) {
        const float4 f0 = rp2[lane + 128 * d];       // c = 2d
        const float4 f1 = rp2[lane + 64 + 128 * d];  // c = 2d+1
        if (mat == 0) {
          acc[8 * d + 0] += f0.x * sinv; acc[8 * d + 1] += f0.y * sinv;
          acc[8 * d + 2] += f0.z * sinv; acc[8 * d + 3] += f0.w * sinv;
          acc[8 * d + 4] += f1.x * sinv; acc[8 * d + 5] += f1.y * sinv;
          acc[8 * d + 6] += f1.z * sinv; acc[8 * d + 7] += f1.w * sinv;
        }
        w[d] = pack8_fp4(f0, f1, s4);
      }
      *(uintx4*)&q4[row * 256 + lane * 4] = w;  // 16B/lane, 1KB/wave
    }
  }
  if (mat == 2) return;  // uniform per block — no divergent barrier

  // cross-wave combine, then one device atomic per column per block.
  __shared__ float lsum[4][2048];
  #pragma unroll
  for (int c = 0; c < 8; c++)
    *(floatx4*)&lsum[wave][4 * lane + 256 * c] =
        floatx4{acc[4 * c], acc[4 * c + 1], acc[4 * c + 2], acc[4 * c + 3]};
  __syncthreads();
  float* dst = (mat == 0) ? s_a : s_b;
  #pragma unroll
  for (int k = 0; k < 8; k++) {
    const int col = tid + 256 * k;
    atomicAdd(&dst[col],
              lsum[0][col] + lsum[1][col] + lsum[2][col] + lsum[3][col]);
  }
}

// ---------------------------------------------------------------------------
// Kernel 2: MX-fp4 MFMA GEMM a_n @ c_n^T with fused sum(exp(sim/T)) epilogue.
// UNCHANGED from r12 (single-variable discipline).
// Keeps: dbuf, XOR source-swizzle, bijective XCD-chunk swizzle, occupancy 2,
// 32x32x64 fp4 MFMA.
// grid (32, 32), block 256 (4 waves; each wave owns a 64x64 quadrant).
// ---------------------------------------------------------------------------
__global__ __launch_bounds__(256, 2) void gemm_expsum_kernel(
    const unsigned char* __restrict__ a4, const unsigned char* __restrict__ c4,
    float* __restrict__ S_part) {
  __shared__ unsigned char As[2][128 * 128];  // [buf][row][chunk^(row&7)]
  __shared__ unsigned char Cs[2][128 * 128];
  const int tid = threadIdx.x;
  const int lane = tid & 63;
  const int wave = tid >> 6;
  const int wr = wave >> 1;       // wave row quadrant (0/1)
  const int wc = wave & 1;        // wave col quadrant (0/1)
  const int half = lane >> 5;     // k-half selector within a k-step (K=64)
  const int l32 = lane & 31;

  // XCD-chunked swizzle (bijective: 1024 = 8 chunks x 128 blocks)
  const int lin = blockIdx.y * 32 + blockIdx.x;
  const int xcd = lin & 7;        // HW assigns lin -> XCD round-robin
  const int idx = lin >> 3;       // 0..127 within this XCD's chunk
  const int br = (xcd >> 1) * 8 + (idx >> 4);   // 4 chunk-rows of 8
  const int bc = (xcd & 1) * 16 + (idx & 15);   // 2 chunk-cols of 16

  floatx16 acc[2][2] = {};

  // staging: per matrix+buffer, 16 windows of 1KB (8 rows x 128B); 4/wave.
  // fp4 row = 1024B; ktile kt covers row bytes [kt*128, kt*128+128).
  const int wrow = lane >> 3;
  const int csrc = (lane & 7) ^ (wrow & 7);
  const unsigned char* gA[4];
  const unsigned char* gC[4];
  int ldsOff[4];
  #pragma unroll
  for (int q = 0; q < 4; q++) {
    const int m = wave * 4 + q;
    const int row = m * 8 + wrow;
    gA[q] = a4 + (size_t)(br * 128 + row) * 1024 + csrc * 16;
    gC[q] = c4 + (size_t)(bc * 128 + row) * 1024 + csrc * 16;
    ldsOff[q] = m * 1024;
  }

  // prologue: stage ktile 0 into buffer 0
  #pragma unroll
  for (int q = 0; q < 4; q++) {
    async_copy16(gA[q], &As[0][ldsOff[q]]);
    async_copy16(gC[q], &Cs[0][ldsOff[q]]);
    gA[q] += 128; gC[q] += 128;
  }

  const int NKT = DD / 256;  // 8 ktiles
  #pragma unroll 2
  for (int kt = 0; kt < NKT; kt++) {
    const int cur = kt & 1;
    __syncthreads();  // drains vmcnt: ktile-kt stage (issued one body ago)

    if (kt < NKT - 1) {  // prefetch kt+1 into the other buffer
      #pragma unroll
      for (int q = 0; q < 4; q++) {
        async_copy16(gA[q], &As[cur ^ 1][ldsOff[q]]);
        async_copy16(gC[q], &Cs[cur ^ 1][ldsOff[q]]);
        gA[q] += 128; gC[q] += 128;
      }
    }

    // fragments: k-step s (64 k-elems = 32B/row), lane(half,l32): 32 nibbles
    // = 16B at logical chunk s*2+half (physical ^(r&7)). fp4 uses v[0:3].
    int4v af[4][2], bf[4][2];
    #pragma unroll
    for (int s = 0; s < 4; s++) {
      #pragma unroll
      for (int i = 0; i < 2; i++) {
        const int r = wr * 64 + i * 32 + l32;
        const int pc = (s * 2 + half) ^ (r & 7);
        af[s][i] = *(const int4v*)&As[cur][r * 128 + pc * 16];
      }
      #pragma unroll
      for (int j = 0; j < 2; j++) {
        const int r = wc * 64 + j * 32 + l32;
        const int pc = (s * 2 + half) ^ (r & 7);
        bf[s][j] = *(const int4v*)&Cs[cur][r * 128 + pc * 16];
      }
    }
    #pragma unroll
    for (int s = 0; s < 4; s++)
      #pragma unroll
      for (int i = 0; i < 2; i++) {
        const int8v a8v = int8v{af[s][i][0], af[s][i][1], af[s][i][2],
                                af[s][i][3], 0, 0, 0, 0};
        #pragma unroll
        for (int j = 0; j < 2; j++) {
          const int8v b8v = int8v{bf[s][j][0], bf[s][j][1], bf[s][j][2],
                                  bf[s][j][3], 0, 0, 0, 0};
          acc[i][j] = __builtin_amdgcn_mfma_scale_f32_32x32x64_f8f6f4(
              a8v, b8v, acc[i][j], 4 /*cbsz: fp4*/, 4 /*blgp: fp4*/,
              0, 0x7F7F7F7F, 0, 0x7F7F7F7F /*E8M0 identity scales*/);
        }
      }
  }

  // epilogue: sum exp(sim/T) over this block's 128x128 tile; acc = 4096*sim.
  float local = 0.f;
  #pragma unroll
  for (int i = 0; i < 2; i++)
    #pragma unroll
    for (int j = 0; j < 2; j++)
      #pragma unroll
      for (int r = 0; r < 16; r++)
        local += __expf(acc[i][j][r] * ACC4_TO_LOGIT);
  #pragma unroll
  for (int off = 32; off > 0; off >>= 1) local += __shfl_down(local, off, 64);
  __shared__ float red[4];
  if (lane == 0) red[wave] = local;
  __syncthreads();
  if (tid == 0) S_part[br * 32 + bc] = red[0] + red[1] + red[2] + red[3];
}

// ---------------------------------------------------------------------------
// Kernel 3: tiny finalize. Separate dispatch => kernel-boundary coherence,
// so plain (non-atomic) reads of s_a/s_b/S_part are safe. 1 block.
// ---------------------------------------------------------------------------
__global__ __launch_bounds__(256) void finalize_kernel(
    const float* __restrict__ s_a, const float* __restrict__ s_b,
    const float* __restrict__ S_part, float* __restrict__ out) {
  const int tid = threadIdx.x;
  float dot = 0.f, se = 0.f;
  #pragma unroll
  for (int k = 0; k < 8; k++)
    dot += s_a[tid + 256 * k] * s_b[tid + 256 * k];
  #pragma unroll
  for (int k = 0; k < 4; k++) se += S_part[tid + 256 * k];
  #pragma unroll
  for (int off = 32; off > 0; off >>= 1) {
    dot += __shfl_down(dot, off, 64);
    se  += __shfl_down(se, off, 64);
  }
  __shared__ float redd[4], reds[4];
  if ((tid & 63) == 0) { redd[tid >> 6] = dot; reds[tid >> 6] = se; }
  __syncthreads();
  if (tid == 0) {
    const float dt = redd[0] + redd[1] + redd[2] + redd[3];
    const float st = reds[0] + reds[1] + reds[2] + reds[3];
    // loss = log(sum exp(sim_neg/T)) - mean(sim_pos)/T
    out[0] = logf(st) - dt * (INV_T / ((float)NR * (float)NR));
  }
}

extern "C" void kernel_launch(void* const* d_in, const int* in_sizes, int n_in,
                              void* d_out, int out_size, void* d_ws, size_t ws_size,
                              hipStream_t stream) {
  const float* src = (const float*)d_in[0];
  const float* bc  = (const float*)d_in[1];
  const float* raw = (const float*)d_in[2];

  char* ws = (char*)d_ws;
  unsigned int* a4 = (unsigned int*)ws;                             // 4 MiB
  unsigned int* c4 = (unsigned int*)(ws + (size_t)4 * 1024 * 1024); // 4 MiB
  float* zb  = (float*)(ws + (size_t)8 * 1024 * 1024);  // s_a | s_b (16 KiB)
  float* s_a = zb;
  float* s_b = zb + DD;
  float* S_part = (float*)(ws + (size_t)8 * 1024 * 1024 + 32 * 1024);  // 4 KiB

  zero_kernel<<<1, 256, 0, stream>>>(zb);
  normalize_colsum_kernel<<<dim3(NR / 16, 3), 256, 0, stream>>>(
      src, bc, raw, a4, c4, s_a, s_b);
  gemm_expsum_kernel<<<dim3(32, 32), 256, 0, stream>>>(
      (const unsigned char*)a4, (const unsigned char*)c4, S_part);
  finalize_kernel<<<1, 256, 0, stream>>>(s_a, s_b, S_part, (float*)d_out);
}

// Round 12
// 150.174 us; speedup vs baseline: 1.2692x; 1.0088x over previous
//
#include <hip/hip_runtime.h>

// Problem constants (N=4096 rows, D=2048 cols, T=0.5 -> 1/T = 2)
#define NR 4096
#define DD 2048
#define INV_T 2.0f
// fp4 path (gemm): a_n*64 ~ N(0,1.41) into e2m1 range ±6 (±4.2 sigma);
// MFMA acc = 4096*sim
#define QS4 64.0f
#define ACC4_TO_LOGIT (INV_T / (QS4 * QS4))  // 2/4096, gemm logits

typedef __attribute__((ext_vector_type(2))) float floatx2;
typedef __attribute__((ext_vector_type(4))) float floatx4;
typedef __attribute__((ext_vector_type(16))) float floatx16;
typedef __attribute__((ext_vector_type(4))) int int4v;
typedef __attribute__((ext_vector_type(8))) int int8v;
typedef __attribute__((ext_vector_type(4))) unsigned int uintx4;

static __device__ __forceinline__ void async_copy16(const void* g, void* lds) {
  __builtin_amdgcn_global_load_lds((const __attribute__((address_space(1))) void*)g,
                                   (__attribute__((address_space(3))) void*)lds,
                                   16, 0, 0);
}

// e2m1 encode of pre-scaled x: values {0,.5,1,1.5,2,3,4,6}, clamp at 6,
// round-to-nearest via midpoint thresholds. Returns 4-bit code.
static __device__ __forceinline__ unsigned int enc4(float x) {
  float u = fminf(fabsf(x), 6.0f);
  int c = (u >= 0.25f) + (u >= 0.75f) + (u >= 1.25f) + (u >= 1.75f) +
          (u >= 2.5f) + (u >= 3.5f) + (u >= 5.0f);
  return (unsigned)(c | (x < 0.f ? 8 : 0));
}

// HW fp4 pack (r20, kept: VALUBusy 22->8%). v_cvt_scalef32_pk_fp4_f32(old,
// s0, s1, scale, byte_sel): fp4(s0)->low nibble, fp4(s1)->high nibble of
// byte byte_sel. scale=1.0 identity; RNE; saturating (same as enc4 clamp).
#if __has_builtin(__builtin_amdgcn_cvt_scalef32_pk_fp4_f32)
static __device__ __forceinline__ unsigned int pack8_fp4(
    const float4& v0, const float4& v1, float s) {
  unsigned int w = 0;
  w = __builtin_amdgcn_cvt_scalef32_pk_fp4_f32(w, v0.x * s, v0.y * s, 1.0f, 0);
  w = __builtin_amdgcn_cvt_scalef32_pk_fp4_f32(w, v0.z * s, v0.w * s, 1.0f, 1);
  w = __builtin_amdgcn_cvt_scalef32_pk_fp4_f32(w, v1.x * s, v1.y * s, 1.0f, 2);
  w = __builtin_amdgcn_cvt_scalef32_pk_fp4_f32(w, v1.z * s, v1.w * s, 1.0f, 3);
  return w;
}
#else
static __device__ __forceinline__ unsigned int pack8_fp4(
    const float4& v0, const float4& v1, float s) {
  return enc4(v0.x * s)        | (enc4(v0.y * s) << 4)  |
         (enc4(v0.z * s) << 8) | (enc4(v0.w * s) << 12) |
         (enc4(v1.x * s) << 16)| (enc4(v1.y * s) << 20) |
         (enc4(v1.z * s) << 24)| (enc4(v1.w * s) << 28);
}
#endif

// ---------------------------------------------------------------------------
// Kernel 0: zero s_a|s_b (4096 floats). Separate dispatch: K1's colsum
// atomics would race with same-kernel zeroing.
// ---------------------------------------------------------------------------
__global__ __launch_bounds__(256) void zero_kernel(float* z) {
  #pragma unroll
  for (int i = 0; i < 4; i++)
    *(floatx4*)&z[4 * (threadIdx.x + 256 * i)] = floatx4{0.f, 0.f, 0.f, 0.f};
}

// ---------------------------------------------------------------------------
// Kernel 1: per-row L2 normalize + fused f32 column sums.
// r21: PER-WAVE ILP fix (theory #7: memory-phase serialization).
// Ledger: 41.3us invariant to TLP (r13), access pattern (r14), VGPR (r19),
// atomics (r16), code size (r20, VALUBusy now 8%). All pipes idle. The only
// untested dimension: each wave's row is a SERIAL chain (8 loads -> waitcnt
// -> reduce -> pack) with just 128B/lane in flight per stall; co-resident
// waves don't fill the gaps (r15: making phases MORE serial -> 70us).
// Fix: batch 2 rows per phase — 16 independent loads in flight (2x),
// independent shfl-reduce chains interleave, half the stalls per wave.
// One-pass (one-pass r12=147.0 beat two-pass r19/r20=151/154 totals).
// mat 0: fp4 a4 + colsum->s_a | mat 1: colsum->s_b | mat 2: fp4 c4.
// col mapping: acc[4c+i] <-> column 4*lane + 256*c + i; fp4 pack order is a
// k-permutation shared by a4/c4 => gemm dot products invariant.
// grid (256, 3), block 256, 16 rows/block (4/wave, 2 batches of 2).
// ---------------------------------------------------------------------------
__global__ __launch_bounds__(256) void normalize_colsum_kernel(
    const float* __restrict__ src, const float* __restrict__ bc,
    const float* __restrict__ raw,
    unsigned int* __restrict__ a4, unsigned int* __restrict__ c4,
    float* __restrict__ s_a, float* __restrict__ s_b) {
  const int mat = blockIdx.y;
  const int tid = threadIdx.x;
  const int lane = tid & 63;
  const int wave = tid >> 6;
  const float* base = (mat == 0) ? src : ((mat == 1) ? bc : raw);
  unsigned int* q4 = (mat == 0) ? a4 : c4;  // unused for mat 1

  // acc[4c+i] accumulates column 4*lane + 256*c + i  (c<8, i<4)
  float acc[32];
  #pragma unroll
  for (int i = 0; i < 32; i++) acc[i] = 0.f;

  #pragma unroll 1   // rolled: keep I-footprint small (r20 lesson held)
  for (int b = 0; b < 2; b++) {
    const int rowA = blockIdx.x * 16 + wave * 4 + b * 2;
    const float4* rpA = (const float4*)(base + (size_t)rowA * DD);
    const float4* rpB = (const float4*)(base + (size_t)(rowA + 1) * DD);

    // 16 independent loads issue back-to-back (2 rows in flight)
    float4 vA[8], vB[8];
    #pragma unroll
    for (int c = 0; c < 8; c++) {
      vA[c] = rpA[lane + 64 * c];
      vB[c] = rpB[lane + 64 * c];
    }
    float ssA = 0.f, ssB = 0.f;
    #pragma unroll
    for (int c = 0; c < 8; c++) {
      ssA += vA[c].x * vA[c].x + vA[c].y * vA[c].y +
             vA[c].z * vA[c].z + vA[c].w * vA[c].w;
      ssB += vB[c].x * vB[c].x + vB[c].y * vB[c].y +
             vB[c].z * vB[c].z + vB[c].w * vB[c].w;
    }
    // two independent reduce chains — interleave, one latency
    #pragma unroll
    for (int off = 1; off < 64; off <<= 1) {
      ssA += __shfl_xor(ssA, off, 64);
      ssB += __shfl_xor(ssB, off, 64);
    }
    const float sinvA = rsqrtf(ssA);
    const float sinvB = rsqrtf(ssB);

    if (mat != 2) {  // f32 colsum accumulate (exact), both rows
      #pragma unroll
      for (int c = 0; c < 8; c++) {
        acc[c * 4 + 0] += (vA[c].x * sinvA + vB[c].x * sinvB);
        acc[c * 4 + 1] += (vA[c].y * sinvA + vB[c].y * sinvB);
        acc[c * 4 + 2] += (vA[c].z * sinvA + vB[c].z * sinvB);
        acc[c * 4 + 3] += (vA[c].w * sinvA + vB[c].w * sinvB);
      }
    }
    if (mat != 1) {  // fp4 pack both rows; one 16B store per row per lane
      const float s4A = sinvA * QS4;
      const float s4B = sinvB * QS4;
      uintx4 wA, wB;
      #pragma unroll
      for (int d = 0; d < 4; d++) {
        wA[d] = pack8_fp4(vA[2 * d], vA[2 * d + 1], s4A);
        wB[d] = pack8_fp4(vB[2 * d], vB[2 * d + 1], s4B);
      }
      *(uintx4*)&q4[rowA * 256 + lane * 4] = wA;
      *(uintx4*)&q4[(rowA + 1) * 256 + lane * 4] = wB;
    }
  }
  if (mat == 2) return;  // uniform per block — no divergent barrier

  // cross-wave combine, then one device atomic per column per block.
  __shared__ float lsum[4][2048];
  #pragma unroll
  for (int c = 0; c < 8; c++)
    *(floatx4*)&lsum[wave][4 * lane + 256 * c] =
        floatx4{acc[4 * c], acc[4 * c + 1], acc[4 * c + 2], acc[4 * c + 3]};
  __syncthreads();
  float* dst = (mat == 0) ? s_a : s_b;
  #pragma unroll
  for (int k = 0; k < 8; k++) {
    const int col = tid + 256 * k;
    atomicAdd(&dst[col],
              lsum[0][col] + lsum[1][col] + lsum[2][col] + lsum[3][col]);
  }
}

// ---------------------------------------------------------------------------
// Kernel 2: MX-fp4 MFMA GEMM a_n @ c_n^T with fused sum(exp(sim/T)) epilogue.
// UNCHANGED from r12 (single-variable discipline).
// Keeps: dbuf, XOR source-swizzle, bijective XCD-chunk swizzle, occupancy 2,
// 32x32x64 fp4 MFMA.
// grid (32, 32), block 256 (4 waves; each wave owns a 64x64 quadrant).
// ---------------------------------------------------------------------------
__global__ __launch_bounds__(256, 2) void gemm_expsum_kernel(
    const unsigned char* __restrict__ a4, const unsigned char* __restrict__ c4,
    float* __restrict__ S_part) {
  __shared__ unsigned char As[2][128 * 128];  // [buf][row][chunk^(row&7)]
  __shared__ unsigned char Cs[2][128 * 128];
  const int tid = threadIdx.x;
  const int lane = tid & 63;
  const int wave = tid >> 6;
  const int wr = wave >> 1;       // wave row quadrant (0/1)
  const int wc = wave & 1;        // wave col quadrant (0/1)
  const int half = lane >> 5;     // k-half selector within a k-step (K=64)
  const int l32 = lane & 31;

  // XCD-chunked swizzle (bijective: 1024 = 8 chunks x 128 blocks)
  const int lin = blockIdx.y * 32 + blockIdx.x;
  const int xcd = lin & 7;        // HW assigns lin -> XCD round-robin
  const int idx = lin >> 3;       // 0..127 within this XCD's chunk
  const int br = (xcd >> 1) * 8 + (idx >> 4);   // 4 chunk-rows of 8
  const int bc = (xcd & 1) * 16 + (idx & 15);   // 2 chunk-cols of 16

  floatx16 acc[2][2] = {};

  // staging: per matrix+buffer, 16 windows of 1KB (8 rows x 128B); 4/wave.
  // fp4 row = 1024B; ktile kt covers row bytes [kt*128, kt*128+128).
  const int wrow = lane >> 3;
  const int csrc = (lane & 7) ^ (wrow & 7);
  const unsigned char* gA[4];
  const unsigned char* gC[4];
  int ldsOff[4];
  #pragma unroll
  for (int q = 0; q < 4; q++) {
    const int m = wave * 4 + q;
    const int row = m * 8 + wrow;
    gA[q] = a4 + (size_t)(br * 128 + row) * 1024 + csrc * 16;
    gC[q] = c4 + (size_t)(bc * 128 + row) * 1024 + csrc * 16;
    ldsOff[q] = m * 1024;
  }

  // prologue: stage ktile 0 into buffer 0
  #pragma unroll
  for (int q = 0; q < 4; q++) {
    async_copy16(gA[q], &As[0][ldsOff[q]]);
    async_copy16(gC[q], &Cs[0][ldsOff[q]]);
    gA[q] += 128; gC[q] += 128;
  }

  const int NKT = DD / 256;  // 8 ktiles
  #pragma unroll 2
  for (int kt = 0; kt < NKT; kt++) {
    const int cur = kt & 1;
    __syncthreads();  // drains vmcnt: ktile-kt stage (issued one body ago)

    if (kt < NKT - 1) {  // prefetch kt+1 into the other buffer
      #pragma unroll
      for (int q = 0; q < 4; q++) {
        async_copy16(gA[q], &As[cur ^ 1][ldsOff[q]]);
        async_copy16(gC[q], &Cs[cur ^ 1][ldsOff[q]]);
        gA[q] += 128; gC[q] += 128;
      }
    }

    // fragments: k-step s (64 k-elems = 32B/row), lane(half,l32): 32 nibbles
    // = 16B at logical chunk s*2+half (physical ^(r&7)). fp4 uses v[0:3].
    int4v af[4][2], bf[4][2];
    #pragma unroll
    for (int s = 0; s < 4; s++) {
      #pragma unroll
      for (int i = 0; i < 2; i++) {
        const int r = wr * 64 + i * 32 + l32;
        const int pc = (s * 2 + half) ^ (r & 7);
        af[s][i] = *(const int4v*)&As[cur][r * 128 + pc * 16];
      }
      #pragma unroll
      for (int j = 0; j < 2; j++) {
        const int r = wc * 64 + j * 32 + l32;
        const int pc = (s * 2 + half) ^ (r & 7);
        bf[s][j] = *(const int4v*)&Cs[cur][r * 128 + pc * 16];
      }
    }
    #pragma unroll
    for (int s = 0; s < 4; s++)
      #pragma unroll
      for (int i = 0; i < 2; i++) {
        const int8v a8v = int8v{af[s][i][0], af[s][i][1], af[s][i][2],
                                af[s][i][3], 0, 0, 0, 0};
        #pragma unroll
        for (int j = 0; j < 2; j++) {
          const int8v b8v = int8v{bf[s][j][0], bf[s][j][1], bf[s][j][2],
                                  bf[s][j][3], 0, 0, 0, 0};
          acc[i][j] = __builtin_amdgcn_mfma_scale_f32_32x32x64_f8f6f4(
              a8v, b8v, acc[i][j], 4 /*cbsz: fp4*/, 4 /*blgp: fp4*/,
              0, 0x7F7F7F7F, 0, 0x7F7F7F7F /*E8M0 identity scales*/);
        }
      }
  }

  // epilogue: sum exp(sim/T) over this block's 128x128 tile; acc = 4096*sim.
  float local = 0.f;
  #pragma unroll
  for (int i = 0; i < 2; i++)
    #pragma unroll
    for (int j = 0; j < 2; j++)
      #pragma unroll
      for (int r = 0; r < 16; r++)
        local += __expf(acc[i][j][r] * ACC4_TO_LOGIT);
  #pragma unroll
  for (int off = 32; off > 0; off >>= 1) local += __shfl_down(local, off, 64);
  __shared__ float red[4];
  if (lane == 0) red[wave] = local;
  __syncthreads();
  if (tid == 0) S_part[br * 32 + bc] = red[0] + red[1] + red[2] + red[3];
}

// ---------------------------------------------------------------------------
// Kernel 3: tiny finalize. Separate dispatch => kernel-boundary coherence,
// so plain (non-atomic) reads of s_a/s_b/S_part are safe. 1 block.
// ---------------------------------------------------------------------------
__global__ __launch_bounds__(256) void finalize_kernel(
    const float* __restrict__ s_a, const float* __restrict__ s_b,
    const float* __restrict__ S_part, float* __restrict__ out) {
  const int tid = threadIdx.x;
  float dot = 0.f, se = 0.f;
  #pragma unroll
  for (int k = 0; k < 8; k++)
    dot += s_a[tid + 256 * k] * s_b[tid + 256 * k];
  #pragma unroll
  for (int k = 0; k < 4; k++) se += S_part[tid + 256 * k];
  #pragma unroll
  for (int off = 32; off > 0; off >>= 1) {
    dot += __shfl_down(dot, off, 64);
    se  += __shfl_down(se, off, 64);
  }
  __shared__ float redd[4], reds[4];
  if ((tid & 63) == 0) { redd[tid >> 6] = dot; reds[tid >> 6] = se; }
  __syncthreads();
  if (tid == 0) {
    const float dt = redd[0] + redd[1] + redd[2] + redd[3];
    const float st = reds[0] + reds[1] + reds[2] + reds[3];
    // loss = log(sum exp(sim_neg/T)) - mean(sim_pos)/T
    out[0] = logf(st) - dt * (INV_T / ((float)NR * (float)NR));
  }
}

extern "C" void kernel_launch(void* const* d_in, const int* in_sizes, int n_in,
                              void* d_out, int out_size, void* d_ws, size_t ws_size,
                              hipStream_t stream) {
  const float* src = (const float*)d_in[0];
  const float* bc  = (const float*)d_in[1];
  const float* raw = (const float*)d_in[2];

  char* ws = (char*)d_ws;
  unsigned int* a4 = (unsigned int*)ws;                             // 4 MiB
  unsigned int* c4 = (unsigned int*)(ws + (size_t)4 * 1024 * 1024); // 4 MiB
  float* zb  = (float*)(ws + (size_t)8 * 1024 * 1024);  // s_a | s_b (16 KiB)
  float* s_a = zb;
  float* s_b = zb + DD;
  float* S_part = (float*)(ws + (size_t)8 * 1024 * 1024 + 32 * 1024);  // 4 KiB

  zero_kernel<<<1, 256, 0, stream>>>(zb);
  normalize_colsum_kernel<<<dim3(NR / 16, 3), 256, 0, stream>>>(
      src, bc, raw, a4, c4, s_a, s_b);
  gemm_expsum_kernel<<<dim3(32, 32), 256, 0, stream>>>(
      (const unsigned char*)a4, (const unsigned char*)c4, S_part);
  finalize_kernel<<<1, 256, 0, stream>>>(s_a, s_b, S_part, (float*)d_out);
}